// Round 9
// baseline (235.560 us; speedup 1.0000x reference)
//
#include <hip/hip_runtime.h>
#include <hip/hip_bf16.h>

#define NV 100000
#define ND 64
#define NB 4096
#define NL 200
#define MT 13        // m-tiles of 16 rows -> 208 (200 real + 8 zero pad)
#define GRID 512     // persistent blocks (2/CU)
#define NIT 4        // pairs per block: 512*4 = 2048 pairs = 4096 rows

typedef __bf16 bf16_t;
typedef __bf16 bf16x8 __attribute__((ext_vector_type(8)));
typedef __bf16 bf16x4 __attribute__((ext_vector_type(4)));
typedef float f32x4 __attribute__((ext_vector_type(4)));

#define TB_ELEMS ((long)NV * ND)      // bf16 shadow emb table elems (12.8 MB)
#define TBV (TB_ELEMS / 8)            // 800000 vector cvt tasks
#define FT1 (128 * 192)               // fW1T elems (B-frag layout [n][k])
#define FT2 (64 * 128)                // fW2T elems
#define CVT_TASKS (TBV + FT1 + FT2)

// ---- kernel 0: f32->bf16 emb table + transposed bf16 MLP weights ----
__global__ __launch_bounds__(256)
void cvt_kernel(const float* __restrict__ emb,
                const float* __restrict__ fW1,
                const float* __restrict__ fW2,
                bf16_t* __restrict__ tb,
                bf16_t* __restrict__ fW1T,
                bf16_t* __restrict__ fW2T)
{
    long t = (long)blockIdx.x * 256 + threadIdx.x;
    if (t >= CVT_TASKS) return;
    if (t < TBV) {
        long i = t * 8;
        f32x4 a0 = *(const f32x4*)(emb + i);
        f32x4 a1 = *(const f32x4*)(emb + i + 4);
        bf16x8 o;
#pragma unroll
        for (int j = 0; j < 4; ++j) { o[j] = (bf16_t)a0[j]; o[j + 4] = (bf16_t)a1[j]; }
        *(bf16x8*)(tb + i) = o;
    } else {
        int u = (int)(t - TBV);
        if (u < FT1) {                     // fW1T[n][k] = fW1[k][n]
            int n = u / 192, k = u - n * 192;
            fW1T[u] = (bf16_t)fW1[k * 128 + n];
        } else {                           // fW2T[n][k] = fW2[k][n]
            int u2 = u - FT1;
            int n = u2 >> 7, k = u2 & 127;
            fW2T[u2] = (bf16_t)fW2[k * 64 + n];
        }
    }
}

// Persistent fused DIN: 512 blocks x 512 thr, 4 pairs/block, software-
// pipelined gather. Per iteration: next pair's index loads issue after B2
// (hide under softmax/pool), row+tgt loads issue after phase 5 (hide under
// the 4 MLP phases), regs->histA written after phase 9 (histA free since
// B4). Steady-state chain has no exposed gather latency. MLP weights
// loaded once (registers) for all 4 pairs. LDS 76 KB -> 2 blocks/CU.
__global__ __launch_bounds__(512, 4)
void din_kernel1(const int* __restrict__ item_ids,
                 const int* __restrict__ history,
                 const int* __restrict__ hist_len,
                 const float* __restrict__ emb,
                 const bf16_t* __restrict__ tb,
                 const float* __restrict__ aW1,
                 const float* __restrict__ ab1,
                 const float* __restrict__ aW2,
                 const bf16_t* __restrict__ fW1T, const float* __restrict__ fb1,
                 const bf16_t* __restrict__ fW2T, const float* __restrict__ fb2,
                 const float* __restrict__ fW3, const float* __restrict__ fb3,
                 float* __restrict__ out)
{
    __shared__ __align__(16) bf16_t histA[2][208 * 64];   // 53248 B
    __shared__ __align__(16) bf16_t wbT[2][64 * 64];      // 16384 B, wbT[n][k]
    __shared__ float tgt[2][64];
    __shared__ __align__(16) float scores[2][208];
    __shared__ float wts[2][208];
    __shared__ float pp2[2][256];
    __shared__ float red[2][8];
    __shared__ float cb2[2][64];

    // MLP tiles alias wbT (dead after phase 3; B8 guards loop reuse)
    bf16_t* comb16 = (bf16_t*)wbT;                  // [16][200] bf16
    bf16_t* z1s    = (bf16_t*)wbT + 3200;           // [16][136] bf16
    float*  z2f    = (float*)((bf16_t*)wbT + 5376); // [2][64] f32

    const int bid = blockIdx.x;
    const int tid = threadIdx.x;

    // fixed gather roles
    const int p    = tid & 1;     // half-row: 32 bf16 = 64 B
    const int s    = tid >> 1;    // 0..255
    const int bxA  = (s >= 208);
    const int lA   = s - bxA * 208;
    const int lB   = s + 48;
    const bool hasB = (s < 160);

    // fixed MFMA roles
    const int wave = tid >> 6, lane = tid & 63;
    const int col  = lane & 15, quad = lane >> 4;

    // ---- MLP weights: load ONCE for all 4 pairs ----
    bf16x8 bw1[6]; float b1v;
    bf16x8 bw2[4]; float b2v = 0.f;
    {
        const int n = wave * 16 + col;          // 0..127
#pragma unroll
        for (int ks = 0; ks < 6; ++ks)
            bw1[ks] = *(const bf16x8*)&fW1T[(long)n * 192 + ks * 32 + quad * 8];
        b1v = fb1[n];
        if (wave < 4) {
            const int n2 = wave * 16 + col;     // 0..63
#pragma unroll
            for (int ks = 0; ks < 4; ++ks)
                bw2[ks] = *(const bf16x8*)&fW2T[(long)n2 * 128 + ks * 32 + quad * 8];
            b2v = fb2[n2];
        }
    }

    const bf16x8 z8 = (bf16x8)(bf16_t)0.f;

    // ---- prologue: gather pair `bid` ----
    int  pr = bid;
    long it0, it1;                // emb row offsets for cur pair's items
    {
        const int b0 = pr * 2;
        it0 = (long)item_ids[b0] * ND;
        it1 = (long)item_ids[b0 + 1] * ND;
        const int len0 = hist_len[b0], len1 = hist_len[b0 + 1];
        float tg = 0.f;
        if (tid < 128) tg = emb[((tid >> 6) ? it1 : it0) + (tid & 63)];
        const int lenA = bxA ? len1 : len0;
        bf16x8 a0 = z8, a1 = z8, a2 = z8, a3 = z8;
        bf16x8 c0 = z8, c1 = z8, c2 = z8, c3 = z8;
        if (lA < lenA) {
            const bf16_t* src = tb + (long)history[(long)(b0 + bxA) * NL + lA] * ND + p * 32;
            a0 = *(const bf16x8*)(src);      a1 = *(const bf16x8*)(src + 8);
            a2 = *(const bf16x8*)(src + 16); a3 = *(const bf16x8*)(src + 24);
        }
        if (hasB && lB < len1) {
            const bf16_t* src = tb + (long)history[(long)(b0 + 1) * NL + lB] * ND + p * 32;
            c0 = *(const bf16x8*)(src);      c1 = *(const bf16x8*)(src + 8);
            c2 = *(const bf16x8*)(src + 16); c3 = *(const bf16x8*)(src + 24);
        }
        {
            bf16_t* d = &histA[bxA][lA * 64];
            const int S = (lA & 7) << 3;
            *(bf16x8*)&d[(p * 32 +  0) ^ S] = a0;
            *(bf16x8*)&d[(p * 32 +  8) ^ S] = a1;
            *(bf16x8*)&d[(p * 32 + 16) ^ S] = a2;
            *(bf16x8*)&d[(p * 32 + 24) ^ S] = a3;
        }
        if (hasB) {
            bf16_t* d = &histA[1][lB * 64];
            const int S = (lB & 7) << 3;
            *(bf16x8*)&d[(p * 32 +  0) ^ S] = c0;
            *(bf16x8*)&d[(p * 32 +  8) ^ S] = c1;
            *(bf16x8*)&d[(p * 32 + 16) ^ S] = c2;
            *(bf16x8*)&d[(p * 32 + 24) ^ S] = c3;
        }
        if (tid < 128) tgt[tid >> 6][tid & 63] = tg;
    }
    // no barrier needed here: B1 orders these LDS writes before phase-3 reads

    for (int it = 0; it < NIT; ++it) {
        const int b0 = pr * 2;

        // ---- phase 2: Wb^T + cb2, csum reduced in-wave ----
        {
            const int bx = wave & 1;
            const int n  = ((wave >> 1) << 4) | col;
            const int kq = quad;                      // 0..3
            const long t0 = bx ? it1 : it0;
            f32x4 tka = *(const f32x4*)(emb + t0 + kq * 16);
            f32x4 tkb = *(const f32x4*)(emb + t0 + kq * 16 + 4);
            f32x4 tkc = *(const f32x4*)(emb + t0 + kq * 16 + 8);
            f32x4 tkd = *(const f32x4*)(emb + t0 + kq * 16 + 12);
            float csum = 0.f;
            bf16x8 w0v, w1v;
#pragma unroll
            for (int i = 0; i < 16; ++i) {
                int k = kq * 16 + i;
                float tk = (i < 4) ? tka[i] : (i < 8) ? tkb[i - 4]
                         : (i < 12) ? tkc[i - 8] : tkd[i - 12];
                float ah = aW1[k * 64 + n];
                float am = aW1[(64 + k) * 64 + n];
                float ap = aW1[(128 + k) * 64 + n];
                float wv = ah + tk * ap;
                if (i < 8) w0v[i] = (bf16_t)wv; else w1v[i - 8] = (bf16_t)wv;
                csum += tk * am;
            }
            const int S = (n & 7) << 3;
            *(bf16x8*)&wbT[bx][n * 64 + ((kq * 16    ) ^ S)] = w0v;
            *(bf16x8*)&wbT[bx][n * 64 + ((kq * 16 + 8) ^ S)] = w1v;
            csum += __shfl_xor(csum, 16, 64);
            csum += __shfl_xor(csum, 32, 64);
            if (kq == 0) cb2[bx][n] = ab1[n] + csum;
        }
        __syncthreads();   // B1

        // ---- phase 3: S^T = Wb^T @ hist^T via MFMA (bias in C-init) ----
        {
            const int bx = wave & 1;
            bf16x8 afrag[4][2];
#pragma unroll
            for (int nt = 0; nt < 4; ++nt) {
                const int n = nt * 16 + col;
                const int S = (n & 7) << 3;
#pragma unroll
                for (int kb = 0; kb < 2; ++kb)
                    afrag[nt][kb] = *(const bf16x8*)&wbT[bx][n * 64 + ((kb * 32 + quad * 8) ^ S)];
            }
            float cv[4][4], a2[4][4];
#pragma unroll
            for (int nt = 0; nt < 4; ++nt)
#pragma unroll
                for (int i = 0; i < 4; ++i) {
                    const int no = nt * 16 + quad * 4 + i;
                    cv[nt][i] = cb2[bx][no];
                    a2[nt][i] = aW2[no];
                }
            for (int mt = (wave >> 1); mt < MT; mt += 4) {
                const int l = mt * 16 + col;
                const int S = (l & 7) << 3;
                const bf16_t* base = &histA[bx][l * 64];
                bf16x8 bf0 = *(const bf16x8*)&base[(     quad * 8) ^ S];
                bf16x8 bf1 = *(const bf16x8*)&base[(32 + quad * 8) ^ S];
                float sc = 0.f;
#pragma unroll
                for (int nt = 0; nt < 4; ++nt) {
                    f32x4 acc = {cv[nt][0], cv[nt][1], cv[nt][2], cv[nt][3]};
                    acc = __builtin_amdgcn_mfma_f32_16x16x32_bf16(afrag[nt][0], bf0, acc, 0, 0, 0);
                    acc = __builtin_amdgcn_mfma_f32_16x16x32_bf16(afrag[nt][1], bf1, acc, 0, 0, 0);
#pragma unroll
                    for (int i = 0; i < 4; ++i) {
                        float h = acc[i] > 0.f ? acc[i] : 0.f;
                        sc += h * a2[nt][i];
                    }
                }
                sc += __shfl_xor(sc, 16, 64);
                sc += __shfl_xor(sc, 32, 64);
                if (quad == 0) scores[bx][mt * 16 + col] = sc;
            }
        }
        __syncthreads();   // B2

        // ---- pipeline: issue NEXT pair's index/meta loads now ----
        const bool more = (it + 1 < NIT);
        long nit0 = 0, nit1 = 0;
        int  nlenA = 0, nlen1 = 0, idxA = 0, idxB = 0;
        if (more) {
            const int nb0 = (pr + GRID) * 2;
            nit0 = (long)item_ids[nb0] * ND;
            nit1 = (long)item_ids[nb0 + 1] * ND;
            const int nl0 = hist_len[nb0];
            nlen1 = hist_len[nb0 + 1];
            nlenA = bxA ? nlen1 : nl0;
            if (lA < NL) idxA = history[(long)(nb0 + bxA) * NL + lA];
            if (hasB)    idxB = history[(long)(nb0 + 1) * NL + lB];
        }
        __builtin_amdgcn_sched_barrier(0);   // pin issue before phase 4

        // ---- phase 4: one-pass softmax (wave-local e; publish m_w, s_w) ----
        {
            const int bx = tid >> 8, t = tid & 255;
            float sv = (t < NL) ? scores[bx][t] : -1e30f;
            float m = sv;
            for (int off = 32; off > 0; off >>= 1) m = fmaxf(m, __shfl_xor(m, off, 64));
            float e = (t < NL) ? __expf(sv - m) : 0.f;
            if (t < NL) wts[bx][t] = e;
            else if (t < 208) wts[bx][t] = 0.f;
            float ss = e;
            for (int off = 32; off > 0; off >>= 1) ss += __shfl_xor(ss, off, 64);
            if ((t & 63) == 0) { red[bx][t >> 6] = m; red[bx][4 + (t >> 6)] = ss; }
        }
        __syncthreads();   // B3

        // ---- phase 5: pooled partials; rescale by exp(m_w-m)*rtot ----
        {
            const int bx = tid >> 8, t = tid & 255;
            const int c = t & 15, g = t >> 4;
            const int w4 = (tid >> 6) & 3;
            const float m0 = red[bx][0], m1 = red[bx][1], m2 = red[bx][2], m3 = red[bx][3];
            const float mg = fmaxf(fmaxf(m0, m1), fmaxf(m2, m3));
            float sc0 = __expf(m0 - mg), sc1 = __expf(m1 - mg);
            float sc2 = __expf(m2 - mg), sc3 = __expf(m3 - mg);
            const float rtot = 1.f / (sc0 * red[bx][4] + sc1 * red[bx][5] +
                                      sc2 * red[bx][6] + sc3 * red[bx][7]);
            sc0 *= rtot; sc1 *= rtot; sc2 *= rtot; sc3 *= rtot;
            f32x4 acc = {0.f, 0.f, 0.f, 0.f};
#pragma unroll
            for (int j = 0; j < 13; ++j) {
                const int l = g + j * 16;
                const float scj = (j < 4) ? sc0 : (j < 8) ? sc1 : (j < 12) ? sc2 : sc3;
                const float wl = wts[bx][l] * scj;
                bf16x4 v = *(const bf16x4*)&histA[bx][l * 64 + ((c * 4) ^ ((l & 7) << 3))];
#pragma unroll
                for (int k = 0; k < 4; ++k) acc[k] += wl * (float)v[k];
            }
#pragma unroll
            for (int k = 0; k < 4; ++k) {
                acc[k] += __shfl_xor(acc[k], 16, 64);
                acc[k] += __shfl_xor(acc[k], 32, 64);
            }
            if ((tid & 63) < 16) *(f32x4*)&pp2[bx][w4 * 64 + c * 4] = acc;
        }

        // ---- pipeline: issue NEXT pair's row + tgt loads (hide under MLP) ----
        bf16x8 ra0 = z8, ra1 = z8, ra2 = z8, ra3 = z8;
        bf16x8 rc0 = z8, rc1 = z8, rc2 = z8, rc3 = z8;
        float ntg = 0.f;
        if (more) {
            if (lA < nlenA) {
                const bf16_t* src = tb + (long)idxA * ND + p * 32;
                ra0 = *(const bf16x8*)(src);      ra1 = *(const bf16x8*)(src + 8);
                ra2 = *(const bf16x8*)(src + 16); ra3 = *(const bf16x8*)(src + 24);
            }
            if (hasB && lB < nlen1) {
                const bf16_t* src = tb + (long)idxB * ND + p * 32;
                rc0 = *(const bf16x8*)(src);      rc1 = *(const bf16x8*)(src + 8);
                rc2 = *(const bf16x8*)(src + 16); rc3 = *(const bf16x8*)(src + 24);
            }
            if (tid < 128) ntg = emb[((tid >> 6) ? nit1 : nit0) + (tid & 63)];
        }
        __builtin_amdgcn_sched_barrier(0);   // pin issue before B4
        __syncthreads();   // B4 (wbT dead; MLP aliases go live)

        // ---- phase 6: comb16 rows 0-1 (rows 2-15 garbage, never observed) ----
        {
            const int bx = tid >> 8, t = tid & 255;
            if (t < 192) {
                const int d = t & 63;
                float v;
                if (t < 64) v = tgt[bx][d];
                else {
                    float pl = pp2[bx][d] + pp2[bx][64 + d] + pp2[bx][128 + d] + pp2[bx][192 + d];
                    v = (t < 128) ? pl : pl - tgt[bx][d];
                }
                comb16[bx * 200 + t] = (bf16_t)v;
            }
        }
        __syncthreads();   // B5

        // ---- phase 7: z1 = relu(comb @ fW1 + fb1) via MFMA [192->128] ----
        {
            f32x4 acc = {b1v, b1v, b1v, b1v};
#pragma unroll
            for (int ks = 0; ks < 6; ++ks) {
                bf16x8 a = *(const bf16x8*)&comb16[col * 200 + ks * 32 + quad * 8];
                acc = __builtin_amdgcn_mfma_f32_16x16x32_bf16(a, bw1[ks], acc, 0, 0, 0);
            }
            const int n = wave * 16 + col;
#pragma unroll
            for (int i = 0; i < 4; ++i) {
                const int m = quad * 4 + i;
                if (m < 2) z1s[m * 136 + n] = (bf16_t)fmaxf(acc[i], 0.f);
            }
        }
        __syncthreads();   // B6

        // ---- phase 8: z2 = relu(z1 @ fW2 + fb2) via MFMA [128->64] ----
        if (wave < 4) {
            f32x4 acc = {b2v, b2v, b2v, b2v};
#pragma unroll
            for (int ks = 0; ks < 4; ++ks) {
                bf16x8 a = *(const bf16x8*)&z1s[col * 136 + ks * 32 + quad * 8];
                acc = __builtin_amdgcn_mfma_f32_16x16x32_bf16(a, bw2[ks], acc, 0, 0, 0);
            }
            const int n2 = wave * 16 + col;
#pragma unroll
            for (int i = 0; i < 4; ++i) {
                const int m = quad * 4 + i;
                if (m < 2) z2f[m * 64 + n2] = fmaxf(acc[i], 0.f);
            }
        }
        __syncthreads();   // B7

        // ---- phase 9: out = sigmoid(z2 . fW3 + fb3) ----
        if (tid < 128) {
            const int bx = tid >> 6, j = tid & 63;
            float sv = z2f[bx * 64 + j] * fW3[j];
            for (int off = 32; off > 0; off >>= 1) sv += __shfl_xor(sv, off, 64);
            if (j == 0) out[b0 + bx] = 1.f / (1.f + __expf(-(sv + fb3[0])));
        }

        // ---- pipeline: commit NEXT pair's hist/tgt to LDS ----
        if (more) {
            {
                bf16_t* d = &histA[bxA][lA * 64];
                const int S = (lA & 7) << 3;
                *(bf16x8*)&d[(p * 32 +  0) ^ S] = ra0;
                *(bf16x8*)&d[(p * 32 +  8) ^ S] = ra1;
                *(bf16x8*)&d[(p * 32 + 16) ^ S] = ra2;
                *(bf16x8*)&d[(p * 32 + 24) ^ S] = ra3;
            }
            if (hasB) {
                bf16_t* d = &histA[1][lB * 64];
                const int S = (lB & 7) << 3;
                *(bf16x8*)&d[(p * 32 +  0) ^ S] = rc0;
                *(bf16x8*)&d[(p * 32 +  8) ^ S] = rc1;
                *(bf16x8*)&d[(p * 32 + 16) ^ S] = rc2;
                *(bf16x8*)&d[(p * 32 + 24) ^ S] = rc3;
            }
            if (tid < 128) tgt[tid >> 6][tid & 63] = ntg;
            it0 = nit0; it1 = nit1;
        }
        pr += GRID;
        __syncthreads();   // B8 (z2f read done before next wbT write; histA/tgt visible)
    }
}

extern "C" void kernel_launch(void* const* d_in, const int* in_sizes, int n_in,
                              void* d_out, int out_size, void* d_ws, size_t ws_size,
                              hipStream_t stream) {
    const int*   item_ids = (const int*)d_in[0];
    const int*   history  = (const int*)d_in[1];
    const int*   hist_len = (const int*)d_in[2];
    const float* emb      = (const float*)d_in[3];
    const float* aW1      = (const float*)d_in[4];
    const float* ab1      = (const float*)d_in[5];
    const float* aW2      = (const float*)d_in[6];
    // d_in[7] = ab2: softmax is shift-invariant, exactly cancels -> unused
    const float* fW1      = (const float*)d_in[8];
    const float* fb1      = (const float*)d_in[9];
    const float* fW2      = (const float*)d_in[10];
    const float* fb2      = (const float*)d_in[11];
    const float* fW3      = (const float*)d_in[12];
    const float* fb3      = (const float*)d_in[13];

    // ws layout: bf16 [emb table | fW1T | fW2T], contiguous, 16B-aligned
    bf16_t* tb   = (bf16_t*)d_ws;
    bf16_t* fW1T = tb + TB_ELEMS;
    bf16_t* fW2T = fW1T + FT1;

    cvt_kernel<<<(int)((CVT_TASKS + 255) / 256), 256, 0, stream>>>(emb, fW1, fW2,
                                                                   tb, fW1T, fW2T);
    din_kernel1<<<GRID, 512, 0, stream>>>(item_ids, history, hist_len, emb, tb,
                                          aW1, ab1, aW2,
                                          fW1T, fb1, fW2T, fb2, fW3, fb3,
                                          (float*)d_out);
}

// Round 10
// 233.631 us; speedup vs baseline: 1.0083x; 1.0083x over previous
//
#include <hip/hip_runtime.h>
#include <hip/hip_bf16.h>

#define NV 100000
#define ND 64
#define NB 4096
#define NL 200
#define MT 13        // m-tiles of 16 rows -> 208 (200 real + 8 zero pad)
#define GRID 512     // persistent blocks (2/CU)
#define NIT 4        // pairs per block: 512*4 = 2048 pairs = 4096 rows

typedef __bf16 bf16_t;
typedef __bf16 bf16x8 __attribute__((ext_vector_type(8)));
typedef __bf16 bf16x4 __attribute__((ext_vector_type(4)));
typedef float f32x4 __attribute__((ext_vector_type(4)));

#define TB_ELEMS ((long)NV * ND)      // bf16 shadow emb table elems (12.8 MB)
#define TBV (TB_ELEMS / 8)            // 800000 vector cvt tasks
#define FT1 (128 * 192)               // fW1T elems (B-frag layout [n][k])
#define FT2 (64 * 128)                // fW2T elems
#define CVT_TASKS (TBV + FT1 + FT2)

// ---- kernel 0: f32->bf16 emb table + transposed bf16 MLP weights ----
__global__ __launch_bounds__(256)
void cvt_kernel(const float* __restrict__ emb,
                const float* __restrict__ fW1,
                const float* __restrict__ fW2,
                bf16_t* __restrict__ tb,
                bf16_t* __restrict__ fW1T,
                bf16_t* __restrict__ fW2T)
{
    long t = (long)blockIdx.x * 256 + threadIdx.x;
    if (t >= CVT_TASKS) return;
    if (t < TBV) {
        long i = t * 8;
        f32x4 a0 = *(const f32x4*)(emb + i);
        f32x4 a1 = *(const f32x4*)(emb + i + 4);
        bf16x8 o;
#pragma unroll
        for (int j = 0; j < 4; ++j) { o[j] = (bf16_t)a0[j]; o[j + 4] = (bf16_t)a1[j]; }
        *(bf16x8*)(tb + i) = o;
    } else {
        int u = (int)(t - TBV);
        if (u < FT1) {                     // fW1T[n][k] = fW1[k][n]
            int n = u / 192, k = u - n * 192;
            fW1T[u] = (bf16_t)fW1[k * 128 + n];
        } else {                           // fW2T[n][k] = fW2[k][n]
            int u2 = u - FT1;
            int n = u2 >> 7, k = u2 & 127;
            fW2T[u2] = (bf16_t)fW2[k * 64 + n];
        }
    }
}

// Persistent fused DIN: 512 blocks x 512 thr, 4 pairs/block, software-
// pipelined gather with SPILL-PROOF staged live ranges (R9 spilled 32
// prefetch VGPRs across the MFMA phases -> 128MB scratch writes):
//   slot-A rows: issue after B3, commit right after B4 (live: phase 5 only)
//   slot-B rows: issue after slot-A commit, commit after phase 7
//   tgt commit rides with slot B (phase 6 reads current tgt!)
// MLP weights in registers for all 4 pairs. LDS 76 KB -> 2 blocks/CU.
__global__ __launch_bounds__(512, 4)
void din_kernel1(const int* __restrict__ item_ids,
                 const int* __restrict__ history,
                 const int* __restrict__ hist_len,
                 const float* __restrict__ emb,
                 const bf16_t* __restrict__ tb,
                 const float* __restrict__ aW1,
                 const float* __restrict__ ab1,
                 const float* __restrict__ aW2,
                 const bf16_t* __restrict__ fW1T, const float* __restrict__ fb1,
                 const bf16_t* __restrict__ fW2T, const float* __restrict__ fb2,
                 const float* __restrict__ fW3, const float* __restrict__ fb3,
                 float* __restrict__ out)
{
    __shared__ __align__(16) bf16_t histA[2][208 * 64];   // 53248 B
    __shared__ __align__(16) bf16_t wbT[2][64 * 64];      // 16384 B, wbT[n][k]
    __shared__ float tgt[2][64];
    __shared__ __align__(16) float scores[2][208];
    __shared__ float wts[2][208];
    __shared__ float pp2[2][256];
    __shared__ float red[2][8];
    __shared__ float cb2[2][64];

    // MLP tiles alias wbT (dead after phase 3; B8 guards loop reuse)
    bf16_t* comb16 = (bf16_t*)wbT;                  // [16][200] bf16
    bf16_t* z1s    = (bf16_t*)wbT + 3200;           // [16][136] bf16
    float*  z2f    = (float*)((bf16_t*)wbT + 5376); // [2][64] f32

    const int bid = blockIdx.x;
    const int tid = threadIdx.x;

    // fixed gather roles
    const int p    = tid & 1;     // half-row: 32 bf16 = 64 B
    const int s    = tid >> 1;    // 0..255
    const int bxA  = (s >= 208);
    const int lA   = s - bxA * 208;
    const int lB   = s + 48;
    const bool hasB = (s < 160);

    // fixed MFMA roles
    const int wave = tid >> 6, lane = tid & 63;
    const int col  = lane & 15, quad = lane >> 4;

    // ---- MLP weights: load ONCE for all 4 pairs ----
    bf16x8 bw1[6]; float b1v;
    bf16x8 bw2[4]; float b2v = 0.f;
    {
        const int n = wave * 16 + col;          // 0..127
#pragma unroll
        for (int ks = 0; ks < 6; ++ks)
            bw1[ks] = *(const bf16x8*)&fW1T[(long)n * 192 + ks * 32 + quad * 8];
        b1v = fb1[n];
        if (wave < 4) {
            const int n2 = wave * 16 + col;     // 0..63
#pragma unroll
            for (int ks = 0; ks < 4; ++ks)
                bw2[ks] = *(const bf16x8*)&fW2T[(long)n2 * 128 + ks * 32 + quad * 8];
            b2v = fb2[n2];
        }
    }

    const bf16x8 z8 = (bf16x8)(bf16_t)0.f;

    // ---- prologue: gather pair `bid` (unpipelined) ----
    int  pr = bid;
    long it0, it1;                // emb row offsets for cur pair's items
    {
        const int b0 = pr * 2;
        it0 = (long)item_ids[b0] * ND;
        it1 = (long)item_ids[b0 + 1] * ND;
        const int len0 = hist_len[b0], len1 = hist_len[b0 + 1];
        float tg = 0.f;
        if (tid < 128) tg = emb[((tid >> 6) ? it1 : it0) + (tid & 63)];
        const int lenA = bxA ? len1 : len0;
        bf16x8 a0 = z8, a1 = z8, a2 = z8, a3 = z8;
        bf16x8 c0 = z8, c1 = z8, c2 = z8, c3 = z8;
        if (lA < lenA) {
            const bf16_t* src = tb + (long)history[(long)(b0 + bxA) * NL + lA] * ND + p * 32;
            a0 = *(const bf16x8*)(src);      a1 = *(const bf16x8*)(src + 8);
            a2 = *(const bf16x8*)(src + 16); a3 = *(const bf16x8*)(src + 24);
        }
        if (hasB && lB < len1) {
            const bf16_t* src = tb + (long)history[(long)(b0 + 1) * NL + lB] * ND + p * 32;
            c0 = *(const bf16x8*)(src);      c1 = *(const bf16x8*)(src + 8);
            c2 = *(const bf16x8*)(src + 16); c3 = *(const bf16x8*)(src + 24);
        }
        {
            bf16_t* d = &histA[bxA][lA * 64];
            const int S = (lA & 7) << 3;
            *(bf16x8*)&d[(p * 32 +  0) ^ S] = a0;
            *(bf16x8*)&d[(p * 32 +  8) ^ S] = a1;
            *(bf16x8*)&d[(p * 32 + 16) ^ S] = a2;
            *(bf16x8*)&d[(p * 32 + 24) ^ S] = a3;
        }
        if (hasB) {
            bf16_t* d = &histA[1][lB * 64];
            const int S = (lB & 7) << 3;
            *(bf16x8*)&d[(p * 32 +  0) ^ S] = c0;
            *(bf16x8*)&d[(p * 32 +  8) ^ S] = c1;
            *(bf16x8*)&d[(p * 32 + 16) ^ S] = c2;
            *(bf16x8*)&d[(p * 32 + 24) ^ S] = c3;
        }
        if (tid < 128) tgt[tid >> 6][tid & 63] = tg;
    }
    // no barrier needed here: B1 orders these LDS writes before phase-3 reads

    for (int it = 0; it < NIT; ++it) {
        const int b0 = pr * 2;

        // ---- phase 2: Wb^T + cb2, csum reduced in-wave ----
        {
            const int bx = wave & 1;
            const int n  = ((wave >> 1) << 4) | col;
            const int kq = quad;                      // 0..3
            const long t0 = bx ? it1 : it0;
            f32x4 tka = *(const f32x4*)(emb + t0 + kq * 16);
            f32x4 tkb = *(const f32x4*)(emb + t0 + kq * 16 + 4);
            f32x4 tkc = *(const f32x4*)(emb + t0 + kq * 16 + 8);
            f32x4 tkd = *(const f32x4*)(emb + t0 + kq * 16 + 12);
            float csum = 0.f;
            bf16x8 w0v, w1v;
#pragma unroll
            for (int i = 0; i < 16; ++i) {
                int k = kq * 16 + i;
                float tk = (i < 4) ? tka[i] : (i < 8) ? tkb[i - 4]
                         : (i < 12) ? tkc[i - 8] : tkd[i - 12];
                float ah = aW1[k * 64 + n];
                float am = aW1[(64 + k) * 64 + n];
                float ap = aW1[(128 + k) * 64 + n];
                float wv = ah + tk * ap;
                if (i < 8) w0v[i] = (bf16_t)wv; else w1v[i - 8] = (bf16_t)wv;
                csum += tk * am;
            }
            const int S = (n & 7) << 3;
            *(bf16x8*)&wbT[bx][n * 64 + ((kq * 16    ) ^ S)] = w0v;
            *(bf16x8*)&wbT[bx][n * 64 + ((kq * 16 + 8) ^ S)] = w1v;
            csum += __shfl_xor(csum, 16, 64);
            csum += __shfl_xor(csum, 32, 64);
            if (kq == 0) cb2[bx][n] = ab1[n] + csum;
        }
        __syncthreads();   // B1

        // ---- phase 3: S^T = Wb^T @ hist^T via MFMA (bias in C-init) ----
        {
            const int bx = wave & 1;
            bf16x8 afrag[4][2];
#pragma unroll
            for (int nt = 0; nt < 4; ++nt) {
                const int n = nt * 16 + col;
                const int S = (n & 7) << 3;
#pragma unroll
                for (int kb = 0; kb < 2; ++kb)
                    afrag[nt][kb] = *(const bf16x8*)&wbT[bx][n * 64 + ((kb * 32 + quad * 8) ^ S)];
            }
            float cv[4][4], a2[4][4];
#pragma unroll
            for (int nt = 0; nt < 4; ++nt)
#pragma unroll
                for (int i = 0; i < 4; ++i) {
                    const int no = nt * 16 + quad * 4 + i;
                    cv[nt][i] = cb2[bx][no];
                    a2[nt][i] = aW2[no];
                }
            for (int mt = (wave >> 1); mt < MT; mt += 4) {
                const int l = mt * 16 + col;
                const int S = (l & 7) << 3;
                const bf16_t* base = &histA[bx][l * 64];
                bf16x8 bf0 = *(const bf16x8*)&base[(     quad * 8) ^ S];
                bf16x8 bf1 = *(const bf16x8*)&base[(32 + quad * 8) ^ S];
                float sc = 0.f;
#pragma unroll
                for (int nt = 0; nt < 4; ++nt) {
                    f32x4 acc = {cv[nt][0], cv[nt][1], cv[nt][2], cv[nt][3]};
                    acc = __builtin_amdgcn_mfma_f32_16x16x32_bf16(afrag[nt][0], bf0, acc, 0, 0, 0);
                    acc = __builtin_amdgcn_mfma_f32_16x16x32_bf16(afrag[nt][1], bf1, acc, 0, 0, 0);
#pragma unroll
                    for (int i = 0; i < 4; ++i) {
                        float h = acc[i] > 0.f ? acc[i] : 0.f;
                        sc += h * a2[nt][i];
                    }
                }
                sc += __shfl_xor(sc, 16, 64);
                sc += __shfl_xor(sc, 32, 64);
                if (quad == 0) scores[bx][mt * 16 + col] = sc;
            }
        }
        __syncthreads();   // B2

        // ---- pipeline: next pair's index/meta loads (tiny) ----
        const bool more = (it + 1 < NIT);
        long nit0 = 0, nit1 = 0;
        int  nlenA = 0, nlen1 = 0, idxA = 0, idxB = 0;
        if (more) {
            const int nb0 = (pr + GRID) * 2;
            nit0 = (long)item_ids[nb0] * ND;
            nit1 = (long)item_ids[nb0 + 1] * ND;
            const int nl0 = hist_len[nb0];
            nlen1 = hist_len[nb0 + 1];
            nlenA = bxA ? nlen1 : nl0;
            if (lA < NL) idxA = history[(long)(nb0 + bxA) * NL + lA];
            if (hasB)    idxB = history[(long)(nb0 + 1) * NL + lB];
        }
        __builtin_amdgcn_sched_barrier(0);

        // ---- phase 4: one-pass softmax (wave-local e; publish m_w, s_w) ----
        {
            const int bx = tid >> 8, t = tid & 255;
            float sv = (t < NL) ? scores[bx][t] : -1e30f;
            float m = sv;
            for (int off = 32; off > 0; off >>= 1) m = fmaxf(m, __shfl_xor(m, off, 64));
            float e = (t < NL) ? __expf(sv - m) : 0.f;
            if (t < NL) wts[bx][t] = e;
            else if (t < 208) wts[bx][t] = 0.f;
            float ss = e;
            for (int off = 32; off > 0; off >>= 1) ss += __shfl_xor(ss, off, 64);
            if ((t & 63) == 0) { red[bx][t >> 6] = m; red[bx][4 + (t >> 6)] = ss; }
        }
        __syncthreads();   // B3

        // ---- pipeline: issue slot-A rows (live across phase 5 ONLY) ----
        bf16x8 ra0 = z8, ra1 = z8, ra2 = z8, ra3 = z8;
        float ntg = 0.f;
        if (more) {
            if (lA < nlenA) {
                const bf16_t* src = tb + (long)idxA * ND + p * 32;
                ra0 = *(const bf16x8*)(src);      ra1 = *(const bf16x8*)(src + 8);
                ra2 = *(const bf16x8*)(src + 16); ra3 = *(const bf16x8*)(src + 24);
            }
            if (tid < 128) ntg = emb[((tid >> 6) ? nit1 : nit0) + (tid & 63)];
        }
        __builtin_amdgcn_sched_barrier(0);

        // ---- phase 5: pooled partials; rescale by exp(m_w-m)*rtot ----
        {
            const int bx = tid >> 8, t = tid & 255;
            const int c = t & 15, g = t >> 4;
            const int w4 = (tid >> 6) & 3;
            const float m0 = red[bx][0], m1 = red[bx][1], m2 = red[bx][2], m3 = red[bx][3];
            const float mg = fmaxf(fmaxf(m0, m1), fmaxf(m2, m3));
            float sc0 = __expf(m0 - mg), sc1 = __expf(m1 - mg);
            float sc2 = __expf(m2 - mg), sc3 = __expf(m3 - mg);
            const float rtot = 1.f / (sc0 * red[bx][4] + sc1 * red[bx][5] +
                                      sc2 * red[bx][6] + sc3 * red[bx][7]);
            sc0 *= rtot; sc1 *= rtot; sc2 *= rtot; sc3 *= rtot;
            f32x4 acc = {0.f, 0.f, 0.f, 0.f};
#pragma unroll
            for (int j = 0; j < 13; ++j) {
                const int l = g + j * 16;
                const float scj = (j < 4) ? sc0 : (j < 8) ? sc1 : (j < 12) ? sc2 : sc3;
                const float wl = wts[bx][l] * scj;
                bf16x4 v = *(const bf16x4*)&histA[bx][l * 64 + ((c * 4) ^ ((l & 7) << 3))];
#pragma unroll
                for (int k = 0; k < 4; ++k) acc[k] += wl * (float)v[k];
            }
#pragma unroll
            for (int k = 0; k < 4; ++k) {
                acc[k] += __shfl_xor(acc[k], 16, 64);
                acc[k] += __shfl_xor(acc[k], 32, 64);
            }
            if ((tid & 63) < 16) *(f32x4*)&pp2[bx][w4 * 64 + c * 4] = acc;
        }
        __syncthreads();   // B4 (histA + wbT dead; MLP aliases go live)

        // ---- pipeline: commit slot A (histA free); then issue slot B ----
        bf16x8 rc0 = z8, rc1 = z8, rc2 = z8, rc3 = z8;
        if (more) {
            {
                bf16_t* d = &histA[bxA][lA * 64];
                const int S = (lA & 7) << 3;
                *(bf16x8*)&d[(p * 32 +  0) ^ S] = ra0;
                *(bf16x8*)&d[(p * 32 +  8) ^ S] = ra1;
                *(bf16x8*)&d[(p * 32 + 16) ^ S] = ra2;
                *(bf16x8*)&d[(p * 32 + 24) ^ S] = ra3;
            }
            if (hasB && lB < nlen1) {
                const bf16_t* src = tb + (long)idxB * ND + p * 32;
                rc0 = *(const bf16x8*)(src);      rc1 = *(const bf16x8*)(src + 8);
                rc2 = *(const bf16x8*)(src + 16); rc3 = *(const bf16x8*)(src + 24);
            }
        }
        __builtin_amdgcn_sched_barrier(0);

        // ---- phase 6: comb16 rows 0-1 (reads CURRENT tgt; rows 2-15 garbage,
        //      never observed: MFMA C-row m depends only on A-row m) ----
        {
            const int bx = tid >> 8, t = tid & 255;
            if (t < 192) {
                const int d = t & 63;
                float v;
                if (t < 64) v = tgt[bx][d];
                else {
                    float pl = pp2[bx][d] + pp2[bx][64 + d] + pp2[bx][128 + d] + pp2[bx][192 + d];
                    v = (t < 128) ? pl : pl - tgt[bx][d];
                }
                comb16[bx * 200 + t] = (bf16_t)v;
            }
        }
        __syncthreads();   // B5

        // ---- phase 7: z1 = relu(comb @ fW1 + fb1) via MFMA [192->128] ----
        {
            f32x4 acc = {b1v, b1v, b1v, b1v};
#pragma unroll
            for (int ks = 0; ks < 6; ++ks) {
                bf16x8 a = *(const bf16x8*)&comb16[col * 200 + ks * 32 + quad * 8];
                acc = __builtin_amdgcn_mfma_f32_16x16x32_bf16(a, bw1[ks], acc, 0, 0, 0);
            }
            const int n = wave * 16 + col;
#pragma unroll
            for (int i = 0; i < 4; ++i) {
                const int m = quad * 4 + i;
                if (m < 2) z1s[m * 136 + n] = (bf16_t)fmaxf(acc[i], 0.f);
            }
        }

        // ---- pipeline: commit slot B + next tgt (tgt read done in phase 6) ----
        if (more) {
            if (hasB) {
                bf16_t* d = &histA[1][lB * 64];
                const int S = (lB & 7) << 3;
                *(bf16x8*)&d[(p * 32 +  0) ^ S] = rc0;
                *(bf16x8*)&d[(p * 32 +  8) ^ S] = rc1;
                *(bf16x8*)&d[(p * 32 + 16) ^ S] = rc2;
                *(bf16x8*)&d[(p * 32 + 24) ^ S] = rc3;
            }
            if (tid < 128) tgt[tid >> 6][tid & 63] = ntg;
            it0 = nit0; it1 = nit1;
        }
        __syncthreads();   // B6

        // ---- phase 8: z2 = relu(z1 @ fW2 + fb2) via MFMA [128->64] ----
        if (wave < 4) {
            f32x4 acc = {b2v, b2v, b2v, b2v};
#pragma unroll
            for (int ks = 0; ks < 4; ++ks) {
                bf16x8 a = *(const bf16x8*)&z1s[col * 136 + ks * 32 + quad * 8];
                acc = __builtin_amdgcn_mfma_f32_16x16x32_bf16(a, bw2[ks], acc, 0, 0, 0);
            }
            const int n2 = wave * 16 + col;
#pragma unroll
            for (int i = 0; i < 4; ++i) {
                const int m = quad * 4 + i;
                if (m < 2) z2f[m * 64 + n2] = fmaxf(acc[i], 0.f);
            }
        }
        __syncthreads();   // B7

        // ---- phase 9: out = sigmoid(z2 . fW3 + fb3) ----
        if (tid < 128) {
            const int bx = tid >> 6, j = tid & 63;
            float sv = z2f[bx * 64 + j] * fW3[j];
            for (int off = 32; off > 0; off >>= 1) sv += __shfl_xor(sv, off, 64);
            if (j == 0) out[b0 + bx] = 1.f / (1.f + __expf(-(sv + fb3[0])));
        }

        pr += GRID;
        __syncthreads();   // B8 (z2f read done before next iter's wbT write)
    }
}

extern "C" void kernel_launch(void* const* d_in, const int* in_sizes, int n_in,
                              void* d_out, int out_size, void* d_ws, size_t ws_size,
                              hipStream_t stream) {
    const int*   item_ids = (const int*)d_in[0];
    const int*   history  = (const int*)d_in[1];
    const int*   hist_len = (const int*)d_in[2];
    const float* emb      = (const float*)d_in[3];
    const float* aW1      = (const float*)d_in[4];
    const float* ab1      = (const float*)d_in[5];
    const float* aW2      = (const float*)d_in[6];
    // d_in[7] = ab2: softmax is shift-invariant, exactly cancels -> unused
    const float* fW1      = (const float*)d_in[8];
    const float* fb1      = (const float*)d_in[9];
    const float* fW2      = (const float*)d_in[10];
    const float* fb2      = (const float*)d_in[11];
    const float* fW3      = (const float*)d_in[12];
    const float* fb3      = (const float*)d_in[13];

    // ws layout: bf16 [emb table | fW1T | fW2T], contiguous, 16B-aligned
    bf16_t* tb   = (bf16_t*)d_ws;
    bf16_t* fW1T = tb + TB_ELEMS;
    bf16_t* fW2T = fW1T + FT1;

    cvt_kernel<<<(int)((CVT_TASKS + 255) / 256), 256, 0, stream>>>(emb, fW1, fW2,
                                                                   tb, fW1T, fW2T);
    din_kernel1<<<GRID, 512, 0, stream>>>(item_ids, history, hist_len, emb, tb,
                                          aW1, ab1, aW2,
                                          fW1T, fb1, fW2T, fb2, fW3, fb3,
                                          (float*)d_out);
}

// Round 11
// 145.133 us; speedup vs baseline: 1.6231x; 1.6098x over previous
//
#include <hip/hip_runtime.h>
#include <hip/hip_bf16.h>

#define NV 100000
#define ND 64
#define NB 4096
#define NL 200
#define MT 13        // m-tiles of 16 rows -> 208 (200 real + 8 zero pad)

typedef __bf16 bf16_t;
typedef __bf16 bf16x8 __attribute__((ext_vector_type(8)));
typedef __bf16 bf16x4 __attribute__((ext_vector_type(4)));
typedef float f32x4 __attribute__((ext_vector_type(4)));

#define TB_ELEMS ((long)NV * ND)      // bf16 shadow emb table elems (12.8 MB)
#define TBV (TB_ELEMS / 8)            // 800000 vector cvt tasks
#define FT1 (128 * 192)               // fW1T elems (B-frag layout [n][k])
#define FT2 (64 * 128)                // fW2T elems
#define ZPV 64                        // zero page: 64 x bf16x8 = 1 KB
#define CVT_TASKS (TBV + FT1 + FT2 + ZPV)

// ---- kernel 0: f32->bf16 emb table + transposed bf16 MLP weights + zero page
__global__ __launch_bounds__(256)
void cvt_kernel(const float* __restrict__ emb,
                const float* __restrict__ fW1,
                const float* __restrict__ fW2,
                bf16_t* __restrict__ tb,
                bf16_t* __restrict__ fW1T,
                bf16_t* __restrict__ fW2T,
                bf16_t* __restrict__ zpage)
{
    long t = (long)blockIdx.x * 256 + threadIdx.x;
    if (t >= CVT_TASKS) return;
    if (t < TBV) {
        long i = t * 8;
        f32x4 a0 = *(const f32x4*)(emb + i);
        f32x4 a1 = *(const f32x4*)(emb + i + 4);
        bf16x8 o;
#pragma unroll
        for (int j = 0; j < 4; ++j) { o[j] = (bf16_t)a0[j]; o[j + 4] = (bf16_t)a1[j]; }
        *(bf16x8*)(tb + i) = o;
    } else {
        int u = (int)(t - TBV);
        if (u < FT1) {                     // fW1T[n][k] = fW1[k][n]
            int n = u / 192, k = u - n * 192;
            fW1T[u] = (bf16_t)fW1[k * 128 + n];
        } else if (u < FT1 + FT2) {        // fW2T[n][k] = fW2[k][n]
            int u2 = u - FT1;
            int n = u2 >> 7, k = u2 & 127;
            fW2T[u2] = (bf16_t)fW2[k * 64 + n];
        } else {                           // zero page (masked-gather source)
            int u3 = u - FT1 - FT2;
            *(bf16x8*)(zpage + u3 * 8) = (bf16x8)(bf16_t)0.f;
        }
    }
}

// Fused DIN, 2 batch rows / block (512 thr), R7 structure with ONE change:
// phase-1 gather via global_load_lds (async DMA, zero data VGPRs).
//  - LDS dest linear (base + lane*16); XOR swizzle applied on the GLOBAL
//    source side (rule #21): lane chunk c of row lr reads global chunk
//    c ^ (lr&7). Read path (off ^ ((lr&7)<<3)) unchanged.
//  - masked rows (l >= len) read a zeroed 1KB ws page -> LDS zeros.
//  - ~7 instructions/wave put the whole block's gather in flight at once;
//    latency drains at B1, overlapped by phase 2's aW1 pass.
// LDS 76 KB -> 2 blocks/CU.
__global__ __launch_bounds__(512, 4)
void din_kernel1(const int* __restrict__ item_ids,
                 const int* __restrict__ history,
                 const int* __restrict__ hist_len,
                 const float* __restrict__ emb,
                 const bf16_t* __restrict__ tb,
                 const bf16_t* __restrict__ zpage,
                 const float* __restrict__ aW1,
                 const float* __restrict__ ab1,
                 const float* __restrict__ aW2,
                 const bf16_t* __restrict__ fW1T, const float* __restrict__ fb1,
                 const bf16_t* __restrict__ fW2T, const float* __restrict__ fb2,
                 const float* __restrict__ fW3, const float* __restrict__ fb3,
                 float* __restrict__ out)
{
    __shared__ __align__(16) bf16_t histA[2][208 * 64];   // 53248 B, contiguous
    __shared__ __align__(16) bf16_t wbT[2][64 * 64];      // 16384 B, wbT[n][k]
    __shared__ float tgt[2][64];
    __shared__ __align__(16) float scores[2][208];
    __shared__ float wts[2][208];
    __shared__ float pp2[2][256];
    __shared__ float red[2][8];
    __shared__ float cb2[2][64];

    // MLP tiles alias wbT (dead after phase 3)
    bf16_t* comb16 = (bf16_t*)wbT;                  // [16][200] bf16
    bf16_t* z1s    = (bf16_t*)wbT + 3200;           // [16][136] bf16
    float*  z2f    = (float*)((bf16_t*)wbT + 5376); // [2][64] f32

    const int b0  = blockIdx.x * 2;
    const int tid = threadIdx.x;
    const int len0 = hist_len[b0];
    const int len1 = hist_len[b0 + 1];

    const int wave = tid >> 6, lane = tid & 63;
    const int col  = lane & 15, quad = lane >> 4;

    if (tid < 128) {
        int bx = tid >> 6, d = tid & 63;
        tgt[bx][d] = emb[(long)item_ids[b0 + bx] * ND + d];
    }

    // ---- phase 1: gather 416 row-slots via global_load_lds ----
    // wave w handles slots [w*52, w*52+52): 6 instrs x 8 rows + 1 x 4 rows.
    // slot l: bx = l>=208, lr = l-208*bx; lane covers (row r=lane>>3,
    // chunk c=lane&7); LDS dest = &histA[0][0] + R*64 (+lane*16B linear).
    {
        const int r = lane >> 3;           // row within 8-row group
        const int c = lane & 7;            // 16B chunk within 128B row
#pragma unroll
        for (int j = 0; j < 7; ++j) {
            const int R = wave * 52 + j * 8;
            const int nrows = (j == 6) ? 4 : 8;
            const int l  = R + r;
            const int bx = (l >= 208);
            const int lr = l - (bx ? 208 : 0);
            const int lenx = bx ? len1 : len0;
            const bf16_t* gsrc;
            if (lr < lenx) {
                int idx = history[(long)(b0 + bx) * NL + lr];
                gsrc = tb + (long)idx * ND + ((c ^ (lr & 7)) * 8);
            } else {
                gsrc = zpage + c * 8;
            }
            if (r < nrows) {
                __builtin_amdgcn_global_load_lds(
                    (const __attribute__((address_space(1))) void*)gsrc,
                    (__attribute__((address_space(3))) void*)(&histA[0][0] + (long)R * 64),
                    16, 0, 0);
            }
        }
    }

    // ---- phase 2: Wb^T + cb2, csum reduced in-wave (overlaps gather) ----
    {
        const int bx = wave & 1;
        const int n  = ((wave >> 1) << 4) | col;
        const int kq = quad;                      // 0..3
        const long t0 = (long)item_ids[b0 + bx] * ND;
        f32x4 tka = *(const f32x4*)(emb + t0 + kq * 16);
        f32x4 tkb = *(const f32x4*)(emb + t0 + kq * 16 + 4);
        f32x4 tkc = *(const f32x4*)(emb + t0 + kq * 16 + 8);
        f32x4 tkd = *(const f32x4*)(emb + t0 + kq * 16 + 12);
        float csum = 0.f;
        bf16x8 w0v, w1v;
#pragma unroll
        for (int i = 0; i < 16; ++i) {
            int k = kq * 16 + i;
            float tk = (i < 4) ? tka[i] : (i < 8) ? tkb[i - 4]
                     : (i < 12) ? tkc[i - 8] : tkd[i - 12];
            float ah = aW1[k * 64 + n];
            float am = aW1[(64 + k) * 64 + n];
            float ap = aW1[(128 + k) * 64 + n];
            float wv = ah + tk * ap;
            if (i < 8) w0v[i] = (bf16_t)wv; else w1v[i - 8] = (bf16_t)wv;
            csum += tk * am;
        }
        const int S = (n & 7) << 3;
        *(bf16x8*)&wbT[bx][n * 64 + ((kq * 16    ) ^ S)] = w0v;
        *(bf16x8*)&wbT[bx][n * 64 + ((kq * 16 + 8) ^ S)] = w1v;
        csum += __shfl_xor(csum, 16, 64);
        csum += __shfl_xor(csum, 32, 64);
        if (kq == 0) cb2[bx][n] = ab1[n] + csum;
    }
    __syncthreads();   // B1 (drains gather DMA + wbT/tgt writes)

    // ---- phase 3: S^T = Wb^T @ hist^T via MFMA (bias in C-init) ----
    {
        const int bx = wave & 1;
        bf16x8 afrag[4][2];
#pragma unroll
        for (int nt = 0; nt < 4; ++nt) {
            const int n = nt * 16 + col;
            const int S = (n & 7) << 3;
#pragma unroll
            for (int kb = 0; kb < 2; ++kb)
                afrag[nt][kb] = *(const bf16x8*)&wbT[bx][n * 64 + ((kb * 32 + quad * 8) ^ S)];
        }
        float cv[4][4], a2[4][4];
#pragma unroll
        for (int nt = 0; nt < 4; ++nt)
#pragma unroll
            for (int i = 0; i < 4; ++i) {
                const int no = nt * 16 + quad * 4 + i;
                cv[nt][i] = cb2[bx][no];
                a2[nt][i] = aW2[no];
            }

        for (int mt = (wave >> 1); mt < MT; mt += 4) {
            const int l = mt * 16 + col;     // B-operand n = l
            const int S = (l & 7) << 3;
            const bf16_t* base = &histA[bx][l * 64];
            bf16x8 bf0 = *(const bf16x8*)&base[(     quad * 8) ^ S];
            bf16x8 bf1 = *(const bf16x8*)&base[(32 + quad * 8) ^ S];
            float sc = 0.f;
#pragma unroll
            for (int nt = 0; nt < 4; ++nt) {
                f32x4 acc = {cv[nt][0], cv[nt][1], cv[nt][2], cv[nt][3]};
                acc = __builtin_amdgcn_mfma_f32_16x16x32_bf16(afrag[nt][0], bf0, acc, 0, 0, 0);
                acc = __builtin_amdgcn_mfma_f32_16x16x32_bf16(afrag[nt][1], bf1, acc, 0, 0, 0);
#pragma unroll
                for (int i = 0; i < 4; ++i) {
                    float h = acc[i] > 0.f ? acc[i] : 0.f;
                    sc += h * a2[nt][i];
                }
            }
            sc += __shfl_xor(sc, 16, 64);
            sc += __shfl_xor(sc, 32, 64);
            if (quad == 0) scores[bx][mt * 16 + col] = sc;
        }
    }
    __syncthreads();   // B2

    // ---- phase 4: one-pass softmax (wave-local e; publish m_w, s_w) ----
    {
        const int bx = tid >> 8, t = tid & 255;
        float s = (t < NL) ? scores[bx][t] : -1e30f;
        float m = s;
        for (int off = 32; off > 0; off >>= 1) m = fmaxf(m, __shfl_xor(m, off, 64));
        float e = (t < NL) ? __expf(s - m) : 0.f;     // local to wave max
        if (t < NL) wts[bx][t] = e;
        else if (t < 208) wts[bx][t] = 0.f;           // zero pad for phase 5
        float ss = e;
        for (int off = 32; off > 0; off >>= 1) ss += __shfl_xor(ss, off, 64);
        if ((t & 63) == 0) { red[bx][t >> 6] = m; red[bx][4 + (t >> 6)] = ss; }
    }
    __syncthreads();   // B3

    // prefetch MLP weights to registers (global, L2-hot; no LDS deps)
    bf16x8 bw1[6]; float b1v;
    bf16x8 bw2[4]; float b2v = 0.f;
    {
        const int n = wave * 16 + col;          // 0..127
#pragma unroll
        for (int ks = 0; ks < 6; ++ks)
            bw1[ks] = *(const bf16x8*)&fW1T[(long)n * 192 + ks * 32 + quad * 8];
        b1v = fb1[n];
        if (wave < 4) {
            const int n2 = wave * 16 + col;     // 0..63
#pragma unroll
            for (int ks = 0; ks < 4; ++ks)
                bw2[ks] = *(const bf16x8*)&fW2T[(long)n2 * 128 + ks * 32 + quad * 8];
            b2v = fb2[n2];
        }
    }

    // ---- phase 5: pooled partials; rescale by exp(m_w-m)*rtot inline ----
    // l = g + 16j with g<16  =>  l>>6 == j>>2 (compile-time scale select)
    {
        const int bx = tid >> 8, t = tid & 255;
        const int c = t & 15;         // d = c*4 .. c*4+3
        const int g = t >> 4;         // 0..15 row-groups
        const int w4 = (tid >> 6) & 3;
        const float m0 = red[bx][0], m1 = red[bx][1], m2 = red[bx][2], m3 = red[bx][3];
        const float mg = fmaxf(fmaxf(m0, m1), fmaxf(m2, m3));
        float sc0 = __expf(m0 - mg), sc1 = __expf(m1 - mg);
        float sc2 = __expf(m2 - mg), sc3 = __expf(m3 - mg);
        const float rtot = 1.f / (sc0 * red[bx][4] + sc1 * red[bx][5] +
                                  sc2 * red[bx][6] + sc3 * red[bx][7]);
        sc0 *= rtot; sc1 *= rtot; sc2 *= rtot; sc3 *= rtot;
        f32x4 acc = {0.f, 0.f, 0.f, 0.f};
#pragma unroll
        for (int j = 0; j < 13; ++j) {
            const int l = g + j * 16;
            const float scj = (j < 4) ? sc0 : (j < 8) ? sc1 : (j < 12) ? sc2 : sc3;
            const float wl = wts[bx][l] * scj;
            bf16x4 v = *(const bf16x4*)&histA[bx][l * 64 + ((c * 4) ^ ((l & 7) << 3))];
#pragma unroll
            for (int k = 0; k < 4; ++k) acc[k] += wl * (float)v[k];
        }
#pragma unroll
        for (int k = 0; k < 4; ++k) {
            acc[k] += __shfl_xor(acc[k], 16, 64);
            acc[k] += __shfl_xor(acc[k], 32, 64);
        }
        if ((tid & 63) < 16) *(f32x4*)&pp2[bx][w4 * 64 + c * 4] = acc;
    }
    __syncthreads();   // B4 (wbT dead; MLP aliases go live)

    // ---- phase 6: comb16 rows 0-1 only (rows 2-15 garbage, never observed:
    //      MFMA C-row m depends only on A-row m) ----
    {
        const int bx = tid >> 8, t = tid & 255;
        if (t < 192) {
            const int d = t & 63;
            float v;
            if (t < 64) v = tgt[bx][d];
            else {
                float pl = pp2[bx][d] + pp2[bx][64 + d] + pp2[bx][128 + d] + pp2[bx][192 + d];
                v = (t < 128) ? pl : pl - tgt[bx][d];
            }
            comb16[bx * 200 + t] = (bf16_t)v;
        }
    }
    __syncthreads();   // B5

    // ---- phase 7: z1 = relu(comb @ fW1 + fb1) via MFMA [192->128] ----
    {
        f32x4 acc = {b1v, b1v, b1v, b1v};
#pragma unroll
        for (int ks = 0; ks < 6; ++ks) {
            bf16x8 a = *(const bf16x8*)&comb16[col * 200 + ks * 32 + quad * 8];
            acc = __builtin_amdgcn_mfma_f32_16x16x32_bf16(a, bw1[ks], acc, 0, 0, 0);
        }
        const int n = wave * 16 + col;
#pragma unroll
        for (int i = 0; i < 4; ++i) {
            const int m = quad * 4 + i;
            if (m < 2) z1s[m * 136 + n] = (bf16_t)fmaxf(acc[i], 0.f);
        }
    }
    __syncthreads();   // B6

    // ---- phase 8: z2 = relu(z1 @ fW2 + fb2) via MFMA [128->64] ----
    {
        if (wave < 4) {
            f32x4 acc = {b2v, b2v, b2v, b2v};
#pragma unroll
            for (int ks = 0; ks < 4; ++ks) {
                bf16x8 a = *(const bf16x8*)&z1s[col * 136 + ks * 32 + quad * 8];
                acc = __builtin_amdgcn_mfma_f32_16x16x32_bf16(a, bw2[ks], acc, 0, 0, 0);
            }
            const int n2 = wave * 16 + col;
#pragma unroll
            for (int i = 0; i < 4; ++i) {
                const int m = quad * 4 + i;
                if (m < 2) z2f[m * 64 + n2] = fmaxf(acc[i], 0.f);
            }
        }
    }
    __syncthreads();   // B7

    // ---- phase 9: out = sigmoid(z2 . fW3 + fb3) ----
    if (tid < 128) {
        const int bx = tid >> 6, j = tid & 63;
        float s = z2f[bx * 64 + j] * fW3[j];
        for (int off = 32; off > 0; off >>= 1) s += __shfl_xor(s, off, 64);
        if (j == 0) out[b0 + bx] = 1.f / (1.f + __expf(-(s + fb3[0])));
    }
}

extern "C" void kernel_launch(void* const* d_in, const int* in_sizes, int n_in,
                              void* d_out, int out_size, void* d_ws, size_t ws_size,
                              hipStream_t stream) {
    const int*   item_ids = (const int*)d_in[0];
    const int*   history  = (const int*)d_in[1];
    const int*   hist_len = (const int*)d_in[2];
    const float* emb      = (const float*)d_in[3];
    const float* aW1      = (const float*)d_in[4];
    const float* ab1      = (const float*)d_in[5];
    const float* aW2      = (const float*)d_in[6];
    // d_in[7] = ab2: softmax is shift-invariant, exactly cancels -> unused
    const float* fW1      = (const float*)d_in[8];
    const float* fb1      = (const float*)d_in[9];
    const float* fW2      = (const float*)d_in[10];
    const float* fb2      = (const float*)d_in[11];
    const float* fW3      = (const float*)d_in[12];
    const float* fb3      = (const float*)d_in[13];

    // ws layout: bf16 [emb table | fW1T | fW2T | zero page], 16B-aligned
    bf16_t* tb    = (bf16_t*)d_ws;
    bf16_t* fW1T  = tb + TB_ELEMS;
    bf16_t* fW2T  = fW1T + FT1;
    bf16_t* zpage = fW2T + FT2;

    cvt_kernel<<<(int)((CVT_TASKS + 255) / 256), 256, 0, stream>>>(
        emb, fW1, fW2, tb, fW1T, fW2T, zpage);
    din_kernel1<<<NB / 2, 512, 0, stream>>>(item_ids, history, hist_len, emb, tb,
                                            zpage, aW1, ab1, aW2,
                                            fW1T, fb1, fW2T, fb2, fW3, fb3,
                                            (float*)d_out);
}

// Round 13
// 142.034 us; speedup vs baseline: 1.6585x; 1.0218x over previous
//
#include <hip/hip_runtime.h>
#include <hip/hip_bf16.h>

#define NV 100000
#define ND 64
#define NB 4096
#define NL 200
#define MT 13        // m-tiles of 16 rows -> 208 (200 real + 8 zero pad)

typedef __bf16 bf16_t;
typedef __bf16 bf16x8 __attribute__((ext_vector_type(8)));
typedef __bf16 bf16x4 __attribute__((ext_vector_type(4)));
typedef float f32x4 __attribute__((ext_vector_type(4)));

#define TB_ELEMS ((long)NV * ND)      // bf16 shadow emb table elems (12.8 MB)
#define TBV (TB_ELEMS / 8)            // 800000 vector cvt tasks
#define FT1 (128 * 192)               // fW1T elems (B-frag layout [n][k])
#define FT2 (64 * 128)                // fW2T elems
#define CVT_TASKS (TBV + FT1 + FT2)

// ---- kernel 0: f32->bf16 emb table + transposed bf16 MLP weights ----
__global__ __launch_bounds__(256)
void cvt_kernel(const float* __restrict__ emb,
                const float* __restrict__ fW1,
                const float* __restrict__ fW2,
                bf16_t* __restrict__ tb,
                bf16_t* __restrict__ fW1T,
                bf16_t* __restrict__ fW2T)
{
    long t = (long)blockIdx.x * 256 + threadIdx.x;
    if (t >= CVT_TASKS) return;
    if (t < TBV) {
        long i = t * 8;
        f32x4 a0 = *(const f32x4*)(emb + i);
        f32x4 a1 = *(const f32x4*)(emb + i + 4);
        bf16x8 o;
#pragma unroll
        for (int j = 0; j < 4; ++j) { o[j] = (bf16_t)a0[j]; o[j + 4] = (bf16_t)a1[j]; }
        *(bf16x8*)(tb + i) = o;
    } else {
        int u = (int)(t - TBV);
        if (u < FT1) {                     // fW1T[n][k] = fW1[k][n]
            int n = u / 192, k = u - n * 192;
            fW1T[u] = (bf16_t)fW1[k * 128 + n];
        } else {                           // fW2T[n][k] = fW2[k][n]
            int u2 = u - FT1;
            int n = u2 >> 7, k = u2 & 127;
            fW2T[u2] = (bf16_t)fW2[k * 64 + n];
        }
    }
}

// Fused DIN, 2 batch rows / block (512 thr) — R7 structure + len-aware work:
//  - padded rows (l >= len) have ZERO hist vectors => their score is the
//    analytic constant spad = sum_n relu(cb[n])*aW2[n]; phase 3 runs MFMA
//    only over T = ceil(len/16) tiles (avg ~7 of 13); phase 5 pools only
//    l < len (padded contribution is exactly 0)
//  - T14 gather split: row loads issue BEFORE phase 2, regs->LDS commit
//    AFTER it (idx->row latency hides under the aW1 pass)
// LDS 76 KB -> 2 blocks/CU.
__global__ __launch_bounds__(512, 4)
void din_kernel1(const int* __restrict__ item_ids,
                 const int* __restrict__ history,
                 const int* __restrict__ hist_len,
                 const float* __restrict__ emb,
                 const bf16_t* __restrict__ tb,
                 const float* __restrict__ aW1,
                 const float* __restrict__ ab1,
                 const float* __restrict__ aW2,
                 const bf16_t* __restrict__ fW1T, const float* __restrict__ fb1,
                 const bf16_t* __restrict__ fW2T, const float* __restrict__ fb2,
                 const float* __restrict__ fW3, const float* __restrict__ fb3,
                 float* __restrict__ out)
{
    __shared__ __align__(16) bf16_t histA[2][208 * 64];   // 53248 B
    __shared__ __align__(16) bf16_t wbT[2][64 * 64];      // 16384 B, wbT[n][k]
    __shared__ float tgt[2][64];
    __shared__ __align__(16) float scores[2][208];
    __shared__ float wts[2][208];
    __shared__ float pp2[2][256];
    __shared__ float red[2][8];
    __shared__ float cb2[2][64];
    __shared__ float spadS[2];

    // MLP tiles alias wbT (dead after phase 3)
    bf16_t* comb16 = (bf16_t*)wbT;                  // [16][200] bf16
    bf16_t* z1s    = (bf16_t*)wbT + 3200;           // [16][136] bf16
    float*  z2f    = (float*)((bf16_t*)wbT + 5376); // [2][64] f32

    const int b0  = blockIdx.x * 2;
    const int tid = threadIdx.x;
    const int len0 = hist_len[b0];
    const int len1 = hist_len[b0 + 1];

    const int wave = tid >> 6, lane = tid & 63;
    const int col  = lane & 15, quad = lane >> 4;

    // ---- phase 1a: ISSUE gather + tgt loads (commit deferred past phase 2) --
    const int p  = tid & 1;       // half-row: 32 bf16 = 64 B
    const int s  = tid >> 1;      // 0..255
    const int bxA  = (s >= 208);
    const int lA   = s - bxA * 208;
    const int lB   = s + 48;
    const int lenA = bxA ? len1 : len0;
    const bool vB  = (s < 160);
    const bf16x8 z8 = (bf16x8)(bf16_t)0.f;
    bf16x8 a0 = z8, a1 = z8, a2v = z8, a3 = z8;
    bf16x8 c0 = z8, c1 = z8, c2 = z8, c3 = z8;
    float tg = 0.f;
    if (tid < 128) tg = emb[(long)item_ids[b0 + (tid >> 6)] * ND + (tid & 63)];
    if (lA < lenA) {
        const bf16_t* src = tb + (long)history[(long)(b0 + bxA) * NL + lA] * ND + p * 32;
        a0  = *(const bf16x8*)(src);      a1 = *(const bf16x8*)(src + 8);
        a2v = *(const bf16x8*)(src + 16); a3 = *(const bf16x8*)(src + 24);
    }
    if (vB && lB < len1) {
        const bf16_t* src = tb + (long)history[(long)(b0 + 1) * NL + lB] * ND + p * 32;
        c0 = *(const bf16x8*)(src);      c1 = *(const bf16x8*)(src + 8);
        c2 = *(const bf16x8*)(src + 16); c3 = *(const bf16x8*)(src + 24);
    }
    __builtin_amdgcn_sched_barrier(0);   // loads stay above phase 2

    // ---- phase 2: Wb^T + cb2, csum reduced in-wave ----
    {
        const int bx = wave & 1;
        const int n  = ((wave >> 1) << 4) | col;
        const int kq = quad;                      // 0..3
        const long t0 = (long)item_ids[b0 + bx] * ND;
        f32x4 tka = *(const f32x4*)(emb + t0 + kq * 16);
        f32x4 tkb = *(const f32x4*)(emb + t0 + kq * 16 + 4);
        f32x4 tkc = *(const f32x4*)(emb + t0 + kq * 16 + 8);
        f32x4 tkd = *(const f32x4*)(emb + t0 + kq * 16 + 12);
        float csum = 0.f;
        bf16x8 w0v, w1v;
#pragma unroll
        for (int i = 0; i < 16; ++i) {
            int k = kq * 16 + i;
            float tk = (i < 4) ? tka[i] : (i < 8) ? tkb[i - 4]
                     : (i < 12) ? tkc[i - 8] : tkd[i - 12];
            float ah = aW1[k * 64 + n];
            float am = aW1[(64 + k) * 64 + n];
            float ap = aW1[(128 + k) * 64 + n];
            float wv = ah + tk * ap;
            if (i < 8) w0v[i] = (bf16_t)wv; else w1v[i - 8] = (bf16_t)wv;
            csum += tk * am;
        }
        const int S = (n & 7) << 3;
        *(bf16x8*)&wbT[bx][n * 64 + ((kq * 16    ) ^ S)] = w0v;
        *(bf16x8*)&wbT[bx][n * 64 + ((kq * 16 + 8) ^ S)] = w1v;
        csum += __shfl_xor(csum, 16, 64);
        csum += __shfl_xor(csum, 32, 64);
        if (kq == 0) cb2[bx][n] = ab1[n] + csum;
    }
    __builtin_amdgcn_sched_barrier(0);   // commit stays below phase 2

    // ---- phase 1b: COMMIT gather regs -> LDS ----
    {
        {
            bf16_t* d = &histA[bxA][lA * 64];
            const int S = (lA & 7) << 3;
            *(bf16x8*)&d[(p * 32 +  0) ^ S] = a0;
            *(bf16x8*)&d[(p * 32 +  8) ^ S] = a1;
            *(bf16x8*)&d[(p * 32 + 16) ^ S] = a2v;
            *(bf16x8*)&d[(p * 32 + 24) ^ S] = a3;
        }
        if (vB) {
            bf16_t* d = &histA[1][lB * 64];
            const int S = (lB & 7) << 3;
            *(bf16x8*)&d[(p * 32 +  0) ^ S] = c0;
            *(bf16x8*)&d[(p * 32 +  8) ^ S] = c1;
            *(bf16x8*)&d[(p * 32 + 16) ^ S] = c2;
            *(bf16x8*)&d[(p * 32 + 24) ^ S] = c3;
        }
        if (tid < 128) tgt[tid >> 6][tid & 63] = tg;
    }
    __syncthreads();   // B1

    // ---- phase 3: S^T = Wb^T @ hist^T via MFMA, len-aware tiles ----
    {
        const int bx   = wave & 1;
        const int lenx = bx ? len1 : len0;
        const int T    = (lenx + 15) >> 4;        // occupied tiles, 1..13

        bf16x8 afrag[4][2];
#pragma unroll
        for (int nt = 0; nt < 4; ++nt) {
            const int n = nt * 16 + col;
            const int S = (n & 7) << 3;
#pragma unroll
            for (int kb = 0; kb < 2; ++kb)
                afrag[nt][kb] = *(const bf16x8*)&wbT[bx][n * 64 + ((kb * 32 + quad * 8) ^ S)];
        }
        float cv[4][4], a2[4][4];
#pragma unroll
        for (int nt = 0; nt < 4; ++nt)
#pragma unroll
            for (int i = 0; i < 4; ++i) {
                const int no = nt * 16 + quad * 4 + i;
                cv[nt][i] = cb2[bx][no];
                a2[nt][i] = aW2[no];
            }

        // analytic pad score: zero hist row => acc = cb => spad
        float ps = 0.f;
#pragma unroll
        for (int nt = 0; nt < 4; ++nt)
#pragma unroll
            for (int i = 0; i < 4; ++i)
                ps += fmaxf(cv[nt][i], 0.f) * a2[nt][i];
        ps += __shfl_xor(ps, 16, 64);
        ps += __shfl_xor(ps, 32, 64);
        if (wave < 2 && lane == 0) spadS[bx] = ps;

        for (int mt = (wave >> 1); mt < T; mt += 4) {
            const int l = mt * 16 + col;     // B-operand n = l
            const int S = (l & 7) << 3;
            const bf16_t* base = &histA[bx][l * 64];
            bf16x8 bf0 = *(const bf16x8*)&base[(     quad * 8) ^ S];
            bf16x8 bf1 = *(const bf16x8*)&base[(32 + quad * 8) ^ S];
            float sc = 0.f;
#pragma unroll
            for (int nt = 0; nt < 4; ++nt) {
                f32x4 acc = {cv[nt][0], cv[nt][1], cv[nt][2], cv[nt][3]};
                acc = __builtin_amdgcn_mfma_f32_16x16x32_bf16(afrag[nt][0], bf0, acc, 0, 0, 0);
                acc = __builtin_amdgcn_mfma_f32_16x16x32_bf16(afrag[nt][1], bf1, acc, 0, 0, 0);
#pragma unroll
                for (int i = 0; i < 4; ++i) {
                    float h = acc[i] > 0.f ? acc[i] : 0.f;
                    sc += h * a2[nt][i];
                }
            }
            sc += __shfl_xor(sc, 16, 64);
            sc += __shfl_xor(sc, 32, 64);
            if (quad == 0) scores[bx][mt * 16 + col] = sc;
        }
    }
    __syncthreads();   // B2

    // ---- phase 4: one-pass softmax; pad rows use spad ----
    {
        const int bx = tid >> 8, t = tid & 255;
        const int lx = bx ? len1 : len0;
        const int TT = ((lx + 15) >> 4) << 4;
        float s = (t < NL) ? ((t < TT) ? scores[bx][t] : spadS[bx]) : -1e30f;
        float m = s;
        for (int off = 32; off > 0; off >>= 1) m = fmaxf(m, __shfl_xor(m, off, 64));
        float e = (t < NL) ? __expf(s - m) : 0.f;     // local to wave max
        if (t < NL) wts[bx][t] = e;
        else if (t < 208) wts[bx][t] = 0.f;           // keep pad finite
        float ss = e;
        for (int off = 32; off > 0; off >>= 1) ss += __shfl_xor(ss, off, 64);
        if ((t & 63) == 0) { red[bx][t >> 6] = m; red[bx][4 + (t >> 6)] = ss; }
    }
    __syncthreads();   // B3

    // prefetch MLP weights to registers (global, L2-hot; no LDS deps)
    bf16x8 bw1[6]; float b1v;
    bf16x8 bw2[4]; float b2v = 0.f;
    {
        const int n = wave * 16 + col;          // 0..127
#pragma unroll
        for (int ks = 0; ks < 6; ++ks)
            bw1[ks] = *(const bf16x8*)&fW1T[(long)n * 192 + ks * 32 + quad * 8];
        b1v = fb1[n];
        if (wave < 4) {
            const int n2 = wave * 16 + col;     // 0..63
#pragma unroll
            for (int ks = 0; ks < 4; ++ks)
                bw2[ks] = *(const bf16x8*)&fW2T[(long)n2 * 128 + ks * 32 + quad * 8];
            b2v = fb2[n2];
        }
    }

    // ---- phase 5: pooled partials, len-aware (pad rows contribute 0) ----
    // l = g + 16j with g<16  =>  l>>6 == j>>2 (compile-time scale select)
    {
        const int bx = tid >> 8, t = tid & 255;
        const int lx = bx ? len1 : len0;
        const int c = t & 15;         // d = c*4 .. c*4+3
        const int g = t >> 4;         // 0..15 row-groups
        const int w4 = (tid >> 6) & 3;
        const float m0 = red[bx][0], m1 = red[bx][1], m2 = red[bx][2], m3 = red[bx][3];
        const float mg = fmaxf(fmaxf(m0, m1), fmaxf(m2, m3));
        float sc0 = __expf(m0 - mg), sc1 = __expf(m1 - mg);
        float sc2 = __expf(m2 - mg), sc3 = __expf(m3 - mg);
        const float rtot = 1.f / (sc0 * red[bx][4] + sc1 * red[bx][5] +
                                  sc2 * red[bx][6] + sc3 * red[bx][7]);
        sc0 *= rtot; sc1 *= rtot; sc2 *= rtot; sc3 *= rtot;
        f32x4 acc = {0.f, 0.f, 0.f, 0.f};
#pragma unroll
        for (int j = 0; j < 13; ++j) {
            if ((j << 4) >= lx) break;                 // wave-uniform exit
            const int l = g + j * 16;
            const float scj = (j < 4) ? sc0 : (j < 8) ? sc1 : (j < 12) ? sc2 : sc3;
            const float wl = wts[bx][l] * scj;
            bf16x4 v = *(const bf16x4*)&histA[bx][l * 64 + ((c * 4) ^ ((l & 7) << 3))];
#pragma unroll
            for (int k = 0; k < 4; ++k) acc[k] += wl * (float)v[k];
        }
#pragma unroll
        for (int k = 0; k < 4; ++k) {
            acc[k] += __shfl_xor(acc[k], 16, 64);
            acc[k] += __shfl_xor(acc[k], 32, 64);
        }
        if ((tid & 63) < 16) *(f32x4*)&pp2[bx][w4 * 64 + c * 4] = acc;
    }
    __syncthreads();   // B4 (wbT dead; MLP aliases go live)

    // ---- phase 6: comb16 rows 0-1 only (rows 2-15 garbage, never observed:
    //      MFMA C-row m depends only on A-row m) ----
    {
        const int bx = tid >> 8, t = tid & 255;
        if (t < 192) {
            const int d = t & 63;
            float v;
            if (t < 64) v = tgt[bx][d];
            else {
                float pl = pp2[bx][d] + pp2[bx][64 + d] + pp2[bx][128 + d] + pp2[bx][192 + d];
                v = (t < 128) ? pl : pl - tgt[bx][d];
            }
            comb16[bx * 200 + t] = (bf16_t)v;
        }
    }
    __syncthreads();   // B5

    // ---- phase 7: z1 = relu(comb @ fW1 + fb1) via MFMA [192->128] ----
    {
        f32x4 acc = {b1v, b1v, b1v, b1v};
#pragma unroll
        for (int ks = 0; ks < 6; ++ks) {
            bf16x8 a = *(const bf16x8*)&comb16[col * 200 + ks * 32 + quad * 8];
            acc = __builtin_amdgcn_mfma_f32_16x16x32_bf16(a, bw1[ks], acc, 0, 0, 0);
        }
        const int n = wave * 16 + col;
#pragma unroll
        for (int i = 0; i < 4; ++i) {
            const int m = quad * 4 + i;
            if (m < 2) z1s[m * 136 + n] = (bf16_t)fmaxf(acc[i], 0.f);
        }
    }
    __syncthreads();   // B6

    // ---- phase 8: z2 = relu(z1 @ fW2 + fb2) via MFMA [128->64] ----
    if (wave < 4) {
        f32x4 acc = {b2v, b2v, b2v, b2v};
#pragma unroll
        for (int ks = 0; ks < 4; ++ks) {
            bf16x8 a = *(const bf16x8*)&z1s[col * 136 + ks * 32 + quad * 8];
            acc = __builtin_amdgcn_mfma_f32_16x16x32_bf16(a, bw2[ks], acc, 0, 0, 0);
        }
        const int n2 = wave * 16 + col;
#pragma unroll
        for (int i = 0; i < 4; ++i) {
            const int m = quad * 4 + i;
            if (m < 2) z2f[m * 64 + n2] = fmaxf(acc[i], 0.f);
        }
    }
    __syncthreads();   // B7

    // ---- phase 9: out = sigmoid(z2 . fW3 + fb3) ----
    if (tid < 128) {
        const int bx = tid >> 6, j = tid & 63;
        float sv = z2f[bx * 64 + j] * fW3[j];
        for (int off = 32; off > 0; off >>= 1) sv += __shfl_xor(sv, off, 64);
        if (j == 0) out[b0 + bx] = 1.f / (1.f + __expf(-(sv + fb3[0])));
    }
}

extern "C" void kernel_launch(void* const* d_in, const int* in_sizes, int n_in,
                              void* d_out, int out_size, void* d_ws, size_t ws_size,
                              hipStream_t stream) {
    const int*   item_ids = (const int*)d_in[0];
    const int*   history  = (const int*)d_in[1];
    const int*   hist_len = (const int*)d_in[2];
    const float* emb      = (const float*)d_in[3];
    const float* aW1      = (const float*)d_in[4];
    const float* ab1      = (const float*)d_in[5];
    const float* aW2      = (const float*)d_in[6];
    // d_in[7] = ab2: softmax is shift-invariant, exactly cancels -> unused
    const float* fW1      = (const float*)d_in[8];
    const float* fb1      = (const float*)d_in[9];
    const float* fW2      = (const float*)d_in[10];
    const float* fb2      = (const float*)d_in[11];
    const float* fW3      = (const float*)d_in[12];
    const float* fb3      = (const float*)d_in[13];

    // ws layout: bf16 [emb table | fW1T | fW2T], contiguous, 16B-aligned
    bf16_t* tb   = (bf16_t*)d_ws;
    bf16_t* fW1T = tb + TB_ELEMS;
    bf16_t* fW2T = fW1T + FT1;

    cvt_kernel<<<(int)((CVT_TASKS + 255) / 256), 256, 0, stream>>>(emb, fW1, fW2,
                                                                   tb, fW1T, fW2T);
    din_kernel1<<<NB / 2, 512, 0, stream>>>(item_ids, history, hist_len, emb, tb,
                                            aW1, ab1, aW2,
                                            fW1T, fb1, fW2T, fb2, fW3, fb3,
                                            (float*)d_out);
}